// Round 10
// baseline (1079.002 us; speedup 1.0000x reference)
//
#include <hip/hip_runtime.h>
#include <cstdint>

typedef unsigned short u16;
typedef __attribute__((ext_vector_type(8))) short short8;
typedef __attribute__((ext_vector_type(8))) unsigned short u16x8;
typedef __attribute__((ext_vector_type(4))) float f32x4;

// d_out layout (floats): [xloss(1), nonpadded(1), pred(130048), Q(1), idx(1024)]
#define XLOSS_OFF 0
#define NPAD_OFF  1
#define PRED_OFF  2
#define Q_OFF     130050
#define IDX_OFF   130051

__device__ __forceinline__ float b2f(u16 u){
  union { unsigned int i; float f; } c; c.i = ((unsigned int)u) << 16; return c.f;
}
__device__ __forceinline__ u16 f2b(float f){
  union { float f; unsigned int i; } c; c.f = f;
  unsigned int i = c.i;
  unsigned int r = (i + 0x7FFFu + ((i >> 16) & 1u)) >> 16;
  return (u16)r;
}

#define LOG2E 1.442695040889634f
__device__ __forceinline__ float fast_sigmoid(float x){
  return __builtin_amdgcn_rcpf(1.f + __builtin_amdgcn_exp2f(-LOG2E*x));
}
__device__ __forceinline__ float fast_tanh(float x){
  return 1.f - 2.f*__builtin_amdgcn_rcpf(1.f + __builtin_amdgcn_exp2f((2.f*LOG2E)*x));
}

// ---------------- prep: bf16 weight copies + zero scalar outputs ----------------
__global__ __launch_bounds__(256) void k_prep_w(
    const float* __restrict__ Wf, const float* __restrict__ Wb,
    const float* __restrict__ Wd, const float* __restrict__ Wo,
    u16* __restrict__ oWf, u16* __restrict__ oWb, u16* __restrict__ oWd,
    u16* __restrict__ oWo, float* __restrict__ dout){
  int idx = blockIdx.x*256 + threadIdx.x;
  if (idx == 0){ dout[XLOSS_OFF]=0.f; dout[NPAD_OFF]=0.f; dout[Q_OFF]=0.f; }
  if (idx < 196608) oWf[idx] = f2b(Wf[idx]);
  else if (idx < 393216) oWb[idx-196608] = f2b(Wb[idx-196608]);
  else if (idx < 589824) oWd[idx-393216] = f2b(Wd[idx-393216]);
  else {
    int i = idx - 589824;           // 0..16383 -> padded [64][256]
    int row = i >> 8, k = i & 255;
    oWo[i] = (row < 51) ? f2b(Wo[row*256 + k]) : (u16)0;
  }
}

// ---------------- prep: gi lookup tables G[v][768] (f32) ----------------
__global__ __launch_bounds__(256) void k_prep_g(
    const float* __restrict__ emb_e, const float* __restrict__ emb_d,
    const float* __restrict__ Wih_f, const float* __restrict__ bih_f, const float* __restrict__ bhh_f,
    const float* __restrict__ Wih_b, const float* __restrict__ bih_b, const float* __restrict__ bhh_b,
    const float* __restrict__ Wih_d,
    float* __restrict__ Gf, float* __restrict__ Gb, float* __restrict__ Gd){
  int idx = blockIdx.x*256 + threadIdx.x;   // exactly 3*51*768 threads
  int tab = idx / 39168;
  int rem = idx - tab*39168;
  int v = rem / 768;
  int n = rem - v*768;
  float acc = 0.f;
  if (tab == 0){
    const float* e = emb_e + v*64; const float* w = Wih_f + n*64;
    for (int k=0;k<64;k++) acc += e[k]*w[k];
    acc += bih_f[n] + (n < 512 ? bhh_f[n] : 0.f);
    Gf[rem] = acc;
  } else if (tab == 1){
    const float* e = emb_e + v*64; const float* w = Wih_b + n*64;
    for (int k=0;k<64;k++) acc += e[k]*w[k];
    acc += bih_b[n] + (n < 512 ? bhh_b[n] : 0.f);
    Gb[rem] = acc;
  } else {
    const float* e = emb_d + v*64; const float* w = Wih_d + n*96 + 32;
    for (int k=0;k<64;k++) acc += e[k]*w[k];
    Gd[rem] = acc;
  }
}

// ---------------- GRU scan, 512 threads, weights register-resident (AGPR+VGPR) ----
// 8 waves; wave w owns h-cols {32w+l15, 32w+16+l15} for ALL 3 gates: 48 B-frags.
// Pin split: 4 groups (32 frags = exactly 128 AGPRs) "+a" — the otherwise-unused
// accumulator half of gfx950's unified file — and 2 groups (64 regs) "+v".
// amdgpu_waves_per_eu(2,2): min=max=2 waves/EU, so the allocator has no occupancy
// incentive to squeeze below the 128V+128A budget. Gates fully in-register;
// h f32 in regs; bf16 h double-buffered in LDS (XOR on FULL column). 1 barrier/step.
template<int MODE>
__global__ __launch_bounds__(512)
__attribute__((amdgpu_waves_per_eu(2, 2)))
void k_gru(
    const u16* __restrict__ W0, const u16* __restrict__ W1,
    const float* __restrict__ G0, const float* __restrict__ G1,
    const float* __restrict__ bhh0, const float* __restrict__ bhh1,
    const int* __restrict__ x,
    const float* __restrict__ zc, const float* __restrict__ h0g,
    float* __restrict__ out_h, u16* __restrict__ ys){
  const int tid = threadIdx.x;
  const int lane = tid & 63;
  const int wave = tid >> 6;                 // 0..7
  const int l15 = lane & 15, lhi = lane >> 4;

  bool fwd = true; int gb;
  const u16* W; const float* G; const float* bhh;
  if (MODE == 0){
    int bi = blockIdx.x;
    fwd = bi < 64; gb = fwd ? bi : bi - 64;
    W = fwd ? W0 : W1; G = fwd ? G0 : G1; bhh = fwd ? bhh0 : bhh1;
  } else {
    gb = blockIdx.x; W = W0; G = G0; bhh = bhh0;
  }
  const int b0 = gb * 16;
  const int nT = (MODE == 0) ? 128 : 127;

  __shared__ u16 hbf[2*4096];                       // [2][16 rows][256 cols], swizzled
  __shared__ int xsh[2048];                         // [16][128] tokens
  __shared__ float zcs[(MODE==1) ? (16*772) : 4];   // decoder per-row constants

  const int ca = wave*32 + l15;                     // first owned col
  const int cb2 = ca + 16;                          // second owned col

  // ---- persistent weights: [gate*2+half][kt], 48 x short8 ----
  short8 wgt[6][8];
  #pragma unroll
  for (int g=0; g<3; g++){
    #pragma unroll
    for (int hh=0; hh<2; hh++){
      const u16* p = W + (size_t)(g*256 + wave*32 + hh*16 + l15)*256 + lhi*8;
      #pragma unroll
      for (int kt=0; kt<8; kt++)
        wgt[g*2+hh][kt] = *(const short8*)(p + kt*32);
    }
  }
  // Pin: groups 0..3 (r,z gates) -> AGPRs (4*8*4 = 128 AGPRs exactly, the unused
  // accumulator half of the unified file); groups 4,5 (n gate) -> VGPRs (64).
  // "+a"/"+v" redefine the values -> no rematerialization inside the time loop.
  #pragma unroll
  for (int kt=0; kt<8; kt++){
    asm volatile("" : "+a"(wgt[0][kt]));
    asm volatile("" : "+a"(wgt[1][kt]));
    asm volatile("" : "+a"(wgt[2][kt]));
    asm volatile("" : "+a"(wgt[3][kt]));
    asm volatile("" : "+v"(wgt[4][kt]));
    asm volatile("" : "+v"(wgt[5][kt]));
  }
  const float bn0 = bhh[512 + ca];
  const float bn1 = bhh[512 + cb2];

  // stage tokens
  for (int i = tid; i < 2048; i += 512) xsh[i] = x[b0*128 + i];
  // stage decoder per-row constants
  if (MODE == 1){
    for (int i = tid; i < 12288; i += 512){
      int r = i / 768, col = i - r*768;
      zcs[r*772 + col] = zc[(size_t)(b0+r)*768 + col];
    }
  }

  // init h (f32 regs) + hbf[0]
  float hr0[4], hr1[4];
  #pragma unroll
  for (int r=0;r<4;r++){
    const int row = 4*lhi + r;
    const int sw = (row&7)<<3;
    float v0 = (MODE==0) ? 0.f : h0g[(size_t)(b0+row)*256 + ca];
    float v1 = (MODE==0) ? 0.f : h0g[(size_t)(b0+row)*256 + cb2];
    hr0[r] = v0; hr1[r] = v1;
    hbf[row*256 + (ca  ^ sw)] = f2b(v0);
    hbf[row*256 + (cb2 ^ sw)] = f2b(v1);
  }
  __syncthreads();

  // A-fragment address bases (swizzle folded into two bases + imm offsets)
  const int s  = l15 & 7;
  const int A0 = l15*256 + ((lhi*8) ^ ((s&3)<<3));
  const int b5 = (s & 4) ? 32 : 0;

  int cur = 0;
  for (int t=0; t<nT; ++t){
    const u16* hb = hbf + cur*4096;
    const u16* pe = hb + A0 + b5;   // even k-tiles
    const u16* po = hb + A0 - b5;   // odd  k-tiles

    f32x4 acc[6];
    #pragma unroll
    for (int j=0;j<6;j++) acc[j] = (f32x4){0.f,0.f,0.f,0.f};
    short8 aC = *(const short8*)(pe);
    #pragma unroll
    for (int kt=0; kt<8; kt++){
      short8 aN = aC;
      if (kt < 7){
        const u16* pp = ((kt+1)&1) ? po : pe;
        aN = *(const short8*)(pp + (kt+1)*32);
      }
      #pragma unroll
      for (int j=0;j<6;j++)
        acc[j] = __builtin_amdgcn_mfma_f32_16x16x32_bf16(aC, wgt[j][kt], acc[j], 0,0,0);
      aC = aN;
    }

    const int te = (MODE==0 && !fwd) ? (127 - t) : t;
    u16* nbuf = hbf + (cur^1)*4096;
    #pragma unroll
    for (int r=0;r<4;r++){
      const int row = 4*lhi + r;
      const int tok = xsh[row*128 + te];
      const float* Gp = G + (size_t)tok*768;
      float gr0 = Gp[ca],       gz0 = Gp[256+ca],       gn0 = Gp[512+ca];
      float gr1 = Gp[cb2],      gz1 = Gp[256+cb2],      gn1 = Gp[512+cb2];
      if (MODE==1){
        const float* zp = &zcs[row*772];
        gr0 += zp[ca];        gz0 += zp[256+ca];        gn0 += zp[512+ca];
        gr1 += zp[cb2];       gz1 += zp[256+cb2];       gn1 += zp[512+cb2];
      }
      // half 0 (col ca)
      {
        float rg = fast_sigmoid(acc[0][r] + gr0);
        float zg = fast_sigmoid(acc[2][r] + gz0);
        float nn = fast_tanh(gn0 + rg*(acc[4][r] + bn0));
        hr0[r] = nn + zg*(hr0[r] - nn);
      }
      // half 1 (col cb2)
      {
        float rg = fast_sigmoid(acc[1][r] + gr1);
        float zg = fast_sigmoid(acc[3][r] + gz1);
        float nn = fast_tanh(gn1 + rg*(acc[5][r] + bn1));
        hr1[r] = nn + zg*(hr1[r] - nn);
      }
      const int sw = (row&7)<<3;
      nbuf[row*256 + (ca  ^ sw)] = f2b(hr0[r]);
      nbuf[row*256 + (cb2 ^ sw)] = f2b(hr1[r]);
    }
    __syncthreads();
    if (MODE == 1){
      const int row = tid >> 5;         // 0..15
      const int ch  = tid & 31;         // 8 cols each
      const int e0  = (ch*8) ^ ((row&7)<<3);
      u16x8 v = *(const u16x8*)&nbuf[row*256 + e0];
      *(u16x8*)&ys[((size_t)(b0+row)*127 + t)*256 + ch*8] = v;
    }
    cur ^= 1;
  }

  if (MODE == 0){
    #pragma unroll
    for (int r=0;r<4;r++){
      const int row = 4*lhi + r;
      float* dst = out_h + (size_t)(b0+row)*512 + (fwd ? 0 : 256);
      dst[ca]  = hr0[r];
      dst[cb2] = hr1[r];
    }
  }
}

// ---------------- VQ: z, argmin codebook, Q, idx, decoder h0, zc ----------------
__global__ __launch_bounds__(64) void k_vq(
    const float* __restrict__ outH, const float* __restrict__ Wdown, const float* __restrict__ bdown,
    const float* __restrict__ cb, const float* __restrict__ Wup, const float* __restrict__ bup,
    const float* __restrict__ Wihd, const float* __restrict__ bihd, const float* __restrict__ bhhd,
    float* __restrict__ hidden, float* __restrict__ zc, float* __restrict__ dout){
  const int b = blockIdx.x;
  const int lane = threadIdx.x;
  __shared__ float oh[512];
  __shared__ float zsh[32];
  __shared__ float qsh[32];
  {
    const float* src = outH + (size_t)b*512 + lane*8;
    *(float4*)&oh[lane*8]   = *(const float4*)src;
    *(float4*)&oh[lane*8+4] = *(const float4*)(src+4);
  }
  __syncthreads();
  if (lane < 32){
    float acc = bdown[lane];
    const float* wr = Wdown + lane*512;
    for (int k=0;k<512;k++) acc += wr[k]*oh[k];
    zsh[lane] = acc;
  }
  __syncthreads();
  float bd = 3.4e38f; int bi = 0;
  for (int c8=0;c8<8;c8++){
    const int c = lane*8 + c8;
    const float* cr = cb + c*32;
    float d = 0.f;
    #pragma unroll
    for (int k=0;k<32;k++){ float df = zsh[k]-cr[k]; d += df*df; }
    if (d < bd){ bd = d; bi = c; }
  }
  #pragma unroll
  for (int offm=32; offm>0; offm>>=1){
    float od = __shfl_xor(bd, offm);
    int   oi = __shfl_xor(bi, offm);
    if (od < bd || (od == bd && oi < bi)){ bd = od; bi = oi; }
  }
  if (lane == 0){
    atomicAdd(&dout[Q_OFF], bd * (0.2f/32.f));
    dout[IDX_OFF + b] = (float)bi;
  }
  if (lane < 32) qsh[lane] = cb[(size_t)bi*32 + lane];
  __syncthreads();
  #pragma unroll
  for (int i=0;i<4;i++){
    const int o = lane*4 + i;
    float acc = bup[o];
    const float* wr = Wup + o*32;
    #pragma unroll
    for (int k=0;k<32;k++) acc += wr[k]*qsh[k];
    hidden[(size_t)b*256 + o] = acc;
  }
  #pragma unroll
  for (int i=0;i<12;i++){
    const int o = lane*12 + i;
    float acc = bihd[o] + (o < 512 ? bhhd[o] : 0.f);
    const float* wr = Wihd + (size_t)o*96;
    #pragma unroll
    for (int k=0;k<32;k++) acc += wr[k]*qsh[k];
    zc[(size_t)b*768 + o] = acc;
  }
}

// ---------------- output: logits, log-softmax, nll, argmax ----------------
__global__ __launch_bounds__(256) void k_out(
    const u16* __restrict__ ys, const u16* __restrict__ Wo,
    const float* __restrict__ bout, const int* __restrict__ x,
    float* __restrict__ dout){
  const int tid = threadIdx.x;
  const int w = tid >> 6, lane = tid & 63;
  const int l15 = lane & 15, lhi = lane >> 4;
  __shared__ float lg[4][32][66];
  const int rows0 = blockIdx.x*128 + w*32;
  const f32x4 fz = {0.f,0.f,0.f,0.f};
  #pragma unroll
  for (int mt=0; mt<2; mt++){
    const int rb = rows0 + mt*16;
    f32x4 acc[4];
    #pragma unroll
    for (int nt=0;nt<4;nt++) acc[nt] = fz;
    #pragma unroll
    for (int kt=0; kt<8; kt++){
      short8 a = *(const short8*)&ys[(size_t)(rb + l15)*256 + kt*32 + lhi*8];
      #pragma unroll
      for (int nt=0; nt<4; nt++){
        short8 bb = *(const short8*)&Wo[(size_t)(nt*16 + l15)*256 + kt*32 + lhi*8];
        acc[nt] = __builtin_amdgcn_mfma_f32_16x16x32_bf16(a, bb, acc[nt], 0, 0, 0);
      }
    }
    #pragma unroll
    for (int nt=0;nt<4;nt++){
      const int col = nt*16 + l15;
      const float bo = (col < 51) ? bout[col] : 0.f;
      #pragma unroll
      for (int r=0;r<4;r++){
        float v = (col < 51) ? (acc[nt][r] + bo) : -1e30f;
        lg[w][mt*16 + lhi*4 + r][col] = v;
      }
    }
  }
  __syncthreads();
  float xl = 0.f, ct = 0.f;
  if (lane < 32){
    const int grow = rows0 + lane;
    const float* Lr = &lg[w][lane][0];
    float m = Lr[0]; int am = 0;
    for (int i=1;i<51;i++){ float v = Lr[i]; if (v > m){ m = v; am = i; } }
    float s = 0.f;
    for (int i=0;i<51;i++) s += __expf(Lr[i] - m);
    const int bb = grow / 127;
    const int tt = grow - bb*127;
    const int tgt = x[bb*128 + tt + 1];
    const float nll = (m + __logf(s)) - Lr[tgt];
    const float mk = (tgt != 0) ? 1.f : 0.f;
    dout[PRED_OFF + grow] = (float)am;
    xl = nll * mk; ct = mk;
  }
  #pragma unroll
  for (int off=32; off>0; off>>=1){
    xl += __shfl_xor(xl, off);
    ct += __shfl_xor(ct, off);
  }
  if (lane == 0){
    atomicAdd(&dout[XLOSS_OFF], xl);
    atomicAdd(&dout[NPAD_OFF], ct);
  }
}

extern "C" void kernel_launch(void* const* d_in, const int* in_sizes, int n_in,
                              void* d_out, int out_size, void* d_ws, size_t ws_size,
                              hipStream_t stream){
  (void)in_sizes; (void)n_in; (void)out_size; (void)ws_size;
  const int*   x      = (const int*)  d_in[0];
  const float* emb_e  = (const float*)d_in[1];
  const float* emb_d  = (const float*)d_in[2];
  const float* Wih_f  = (const float*)d_in[3];
  const float* Whh_f  = (const float*)d_in[4];
  const float* bih_f  = (const float*)d_in[5];
  const float* bhh_f  = (const float*)d_in[6];
  const float* Wih_b  = (const float*)d_in[7];
  const float* Whh_b  = (const float*)d_in[8];
  const float* bih_b  = (const float*)d_in[9];
  const float* bhh_b  = (const float*)d_in[10];
  const float* Wdown  = (const float*)d_in[11];
  const float* bdown  = (const float*)d_in[12];
  const float* cbook  = (const float*)d_in[13];
  const float* Wup    = (const float*)d_in[14];
  const float* bup    = (const float*)d_in[15];
  const float* Wih_d  = (const float*)d_in[16];
  const float* Whh_d  = (const float*)d_in[17];
  const float* bih_d  = (const float*)d_in[18];
  const float* bhh_d  = (const float*)d_in[19];
  const float* Wout   = (const float*)d_in[20];
  const float* bout   = (const float*)d_in[21];
  float* dout = (float*)d_out;

  char* ws = (char*)d_ws;
  size_t off = 0;
  auto nxt = [&](size_t bytes)->char*{
    char* r = ws + off;
    off += (bytes + 255) & ~(size_t)255;
    return r;
  };
  u16*   Wf_bf = (u16*)  nxt((size_t)196608*2);
  u16*   Wb_bf = (u16*)  nxt((size_t)196608*2);
  u16*   Wd_bf = (u16*)  nxt((size_t)196608*2);
  float* Gf    = (float*)nxt((size_t)39168*4);
  float* Gb    = (float*)nxt((size_t)39168*4);
  float* Gd    = (float*)nxt((size_t)39168*4);
  u16*   Wo_bf = (u16*)  nxt((size_t)16384*2);
  float* outH  = (float*)nxt((size_t)524288*4);
  float* hid   = (float*)nxt((size_t)262144*4);
  float* zcw   = (float*)nxt((size_t)786432*4);
  u16*   ysb   = (u16*)  nxt((size_t)33292288*2);

  hipLaunchKernelGGL(k_prep_w, dim3(2368), dim3(256), 0, stream,
                     Whh_f, Whh_b, Whh_d, Wout, Wf_bf, Wb_bf, Wd_bf, Wo_bf, dout);
  hipLaunchKernelGGL(k_prep_g, dim3(459), dim3(256), 0, stream,
                     emb_e, emb_d, Wih_f, bih_f, bhh_f, Wih_b, bih_b, bhh_b, Wih_d,
                     Gf, Gb, Gd);
  hipLaunchKernelGGL((k_gru<0>), dim3(128), dim3(512), 0, stream,
                     Wf_bf, Wb_bf, Gf, Gb, bhh_f, bhh_b, x,
                     (const float*)nullptr, (const float*)nullptr, outH, (u16*)nullptr);
  hipLaunchKernelGGL(k_vq, dim3(1024), dim3(64), 0, stream,
                     outH, Wdown, bdown, cbook, Wup, bup, Wih_d, bih_d, bhh_d,
                     hid, zcw, dout);
  hipLaunchKernelGGL((k_gru<1>), dim3(64), dim3(512), 0, stream,
                     Wd_bf, (const u16*)nullptr, Gd, (const float*)nullptr, bhh_d, (const float*)nullptr, x,
                     zcw, hid, (float*)nullptr, ysb);
  hipLaunchKernelGGL(k_out, dim3(1016), dim3(256), 0, stream,
                     ysb, Wo_bf, bout, x, dout);
}

// Round 11
// 578.083 us; speedup vs baseline: 1.8665x; 1.8665x over previous
//
#include <hip/hip_runtime.h>
#include <cstdint>

typedef unsigned short u16;
typedef unsigned int u32;
typedef __attribute__((ext_vector_type(4))) int int4v;
typedef __attribute__((ext_vector_type(8))) short short8;
typedef __attribute__((ext_vector_type(4))) float f32x4;

// d_out layout (floats): [xloss(1), nonpadded(1), pred(130048), Q(1), idx(1024)]
#define XLOSS_OFF 0
#define NPAD_OFF  1
#define PRED_OFF  2
#define Q_OFF     130050
#define IDX_OFF   130051

__device__ __forceinline__ u16 f2b(float f){
  union { float f; unsigned int i; } c; c.f = f;
  unsigned int i = c.i;
  unsigned int r = (i + 0x7FFFu + ((i >> 16) & 1u)) >> 16;
  return (u16)r;
}

#define LOG2E 1.442695040889634f
__device__ __forceinline__ float fast_sigmoid(float x){
  return __builtin_amdgcn_rcpf(1.f + __builtin_amdgcn_exp2f(-LOG2E*x));
}
__device__ __forceinline__ float fast_tanh(float x){
  return 1.f - 2.f*__builtin_amdgcn_rcpf(1.f + __builtin_amdgcn_exp2f((2.f*LOG2E)*x));
}

// ---------------- prep: Wout bf16 copy + zero scalar outputs ----------------
__global__ __launch_bounds__(256) void k_prep_wo(
    const float* __restrict__ Wo, u16* __restrict__ oWo, float* __restrict__ dout){
  int idx = blockIdx.x*256 + threadIdx.x;      // 16384 threads
  if (idx == 0){ dout[XLOSS_OFF]=0.f; dout[NPAD_OFF]=0.f; dout[Q_OFF]=0.f; }
  int row = idx >> 8, k = idx & 255;
  oWo[idx] = (row < 51) ? f2b(Wo[row*256 + k]) : (u16)0;
}

// ---------------- prep: per-row i8 quantization of Whh_{f,b,d} ----------------
// Row n: s = 127/max|W[n,:]|; q = round(W*s); inv[n] = max/127.
__global__ __launch_bounds__(64) void k_prep_q(
    const float* __restrict__ Wf, const float* __restrict__ Wb, const float* __restrict__ Wd,
    signed char* __restrict__ qf, signed char* __restrict__ qb, signed char* __restrict__ qd,
    float* __restrict__ invf, float* __restrict__ invb, float* __restrict__ invd){
  const int row = blockIdx.x;                  // 0..2303
  const int mat = row / 768, r = row - mat*768;
  const float* W = (mat==0 ? Wf : (mat==1 ? Wb : Wd)) + (size_t)r*256;
  signed char* q = (mat==0 ? qf : (mat==1 ? qb : qd)) + (size_t)r*256;
  float* inv     = (mat==0 ? invf : (mat==1 ? invb : invd));
  const int lane = threadIdx.x;
  float4 v = *(const float4*)(W + lane*4);
  float m = fmaxf(fmaxf(fabsf(v.x),fabsf(v.y)), fmaxf(fabsf(v.z),fabsf(v.w)));
  #pragma unroll
  for (int off=32; off>0; off>>=1) m = fmaxf(m, __shfl_xor(m, off));
  m = fmaxf(m, 1e-20f);
  const float s = 127.f / m;
  int a0 = __float2int_rn(v.x*s), a1 = __float2int_rn(v.y*s);
  int a2 = __float2int_rn(v.z*s), a3 = __float2int_rn(v.w*s);
  u32 packed = (a0&255) | ((a1&255)<<8) | ((a2&255)<<16) | ((a3&255)<<24);
  *(u32*)(q + lane*4) = packed;
  if (lane == 0) inv[r] = m * (1.f/127.f);
}

// ---------------- prep: gi lookup tables G[v][768] (f32) ----------------
__global__ __launch_bounds__(256) void k_prep_g(
    const float* __restrict__ emb_e, const float* __restrict__ emb_d,
    const float* __restrict__ Wih_f, const float* __restrict__ bih_f, const float* __restrict__ bhh_f,
    const float* __restrict__ Wih_b, const float* __restrict__ bih_b, const float* __restrict__ bhh_b,
    const float* __restrict__ Wih_d,
    float* __restrict__ Gf, float* __restrict__ Gb, float* __restrict__ Gd){
  int idx = blockIdx.x*256 + threadIdx.x;   // exactly 3*51*768 threads
  int tab = idx / 39168;
  int rem = idx - tab*39168;
  int v = rem / 768;
  int n = rem - v*768;
  float acc = 0.f;
  if (tab == 0){
    const float* e = emb_e + v*64; const float* w = Wih_f + n*64;
    for (int k=0;k<64;k++) acc += e[k]*w[k];
    acc += bih_f[n] + (n < 512 ? bhh_f[n] : 0.f);
    Gf[rem] = acc;
  } else if (tab == 1){
    const float* e = emb_e + v*64; const float* w = Wih_b + n*64;
    for (int k=0;k<64;k++) acc += e[k]*w[k];
    acc += bih_b[n] + (n < 512 ? bhh_b[n] : 0.f);
    Gb[rem] = acc;
  } else {
    const float* e = emb_d + v*64; const float* w = Wih_d + n*96 + 32;
    for (int k=0;k<64;k++) acc += e[k]*w[k];
    Gd[rem] = acc;
  }
}

// ---------------- GRU scan: i8 weights fully register-resident ----------------
// 1024 threads (16 waves), 16 batch rows/block, 1 block/CU (waves_per_eu(4,4)).
// Wave w owns h-cols [16w,16w+16) for ALL 3 gates: 3 n-tiles x 4 k-tiles of
// mfma_i32_16x16x64_i8 -> 48 weight VGPRs, pinned. Exact i32 accumulate,
// per-row dequant scales. Gates fully in-register (acc holds r/z/n for this
// lane's col). h f32 in regs, i8 (scale HS) double-buffered in LDS with a
// 16B-granule XOR swizzle: byte = m*256 + (k ^ ((m&15)<<4)). 1 barrier/step.
template<int MODE>
__global__ __launch_bounds__(1024)
__attribute__((amdgpu_waves_per_eu(4, 4)))
void k_gru(
    const signed char* __restrict__ W0, const signed char* __restrict__ W1,
    const float* __restrict__ I0, const float* __restrict__ I1,
    const float* __restrict__ G0, const float* __restrict__ G1,
    const float* __restrict__ bhh0, const float* __restrict__ bhh1,
    const int* __restrict__ x,
    const float* __restrict__ zc, const float* __restrict__ h0g,
    float* __restrict__ out_h, u16* __restrict__ ys){
  const int tid = threadIdx.x;
  const int lane = tid & 63;
  const int wave = tid >> 6;                 // 0..15
  const int l15 = lane & 15, lhi = lane >> 4;

  bool fwd = true; int gb;
  const signed char* W; const float* G; const float* bhh; const float* invS;
  if (MODE == 0){
    int bi = blockIdx.x;
    fwd = bi < 64; gb = fwd ? bi : bi - 64;
    W = fwd ? W0 : W1; G = fwd ? G0 : G1; bhh = fwd ? bhh0 : bhh1;
    invS = fwd ? I0 : I1;
  } else {
    gb = blockIdx.x; W = W0; G = G0; bhh = bhh0; invS = I0;
  }
  const int b0 = gb * 16;
  const int nT = (MODE == 0) ? 128 : 127;
  const float HS    = (MODE == 0) ? 127.f : 63.f;
  const float invHS = (MODE == 0) ? (1.f/127.f) : (1.f/63.f);

  __shared__ signed char hbf[2*4096];               // [2][16 rows][256 cols], swizzled
  __shared__ int xsh[2048];                         // [16][128] tokens
  __shared__ float zcs[(MODE==1) ? (16*768) : 4];   // decoder per-row constants

  const int c = wave*16 + l15;                      // this lane's h-column

  // ---- persistent weights: 3 gates x 4 k-tiles(K=64), 48 VGPRs, pinned ----
  int4v wq0[4], wq1[4], wq2[4];
  {
    const signed char* p0 = W + (size_t)(c      )*256 + lhi*16;  // gate r row
    const signed char* p1 = W + (size_t)(c + 256)*256 + lhi*16;  // gate z row
    const signed char* p2 = W + (size_t)(c + 512)*256 + lhi*16;  // gate n row
    #pragma unroll
    for (int kt=0; kt<4; kt++){
      wq0[kt] = *(const int4v*)(p0 + kt*64);
      wq1[kt] = *(const int4v*)(p1 + kt*64);
      wq2[kt] = *(const int4v*)(p2 + kt*64);
    }
  }
  #pragma unroll
  for (int kt=0; kt<4; kt++){
    asm volatile("" : "+v"(wq0[kt]));
    asm volatile("" : "+v"(wq1[kt]));
    asm volatile("" : "+v"(wq2[kt]));
  }
  // dequant scales (weight-row scale x h scale) + n-gate bias
  const float isr = invS[c]       * invHS;
  const float isz = invS[256 + c] * invHS;
  const float isn = invS[512 + c] * invHS;
  const float bnv = bhh[512 + c];

  // stage tokens + decoder constants
  for (int i = tid; i < 2048; i += 1024) xsh[i] = x[b0*128 + i];
  if (MODE == 1){
    for (int i = tid; i < 12288; i += 1024) zcs[i] = zc[(size_t)b0*768 + i];
  }

  // init h (f32 regs) + hbf[0] (i8, swizzled)
  float hreg[4];
  #pragma unroll
  for (int r=0;r<4;r++){
    const int m = 4*lhi + r;
    float hv = (MODE==0) ? 0.f : h0g[(size_t)(b0+m)*256 + c];
    hreg[r] = hv;
    int hq = __float2int_rn(fminf(fmaxf(hv*HS, -127.f), 127.f));
    hbf[m*256 + (c ^ ((m&15)<<4))] = (signed char)hq;
  }
  __syncthreads();

  // A-fragment byte offsets (row l15, K-slice kt*64 + lhi*16, XOR-swizzled)
  int aoff[4];
  #pragma unroll
  for (int kt=0; kt<4; kt++)
    aoff[kt] = l15*256 + ((kt*64 + lhi*16) ^ (l15<<4));

  int cur = 0;
  for (int t=0; t<nT; ++t){
    const signed char* hb = hbf + (cur<<12);
    int4v af[4];
    #pragma unroll
    for (int kt=0; kt<4; kt++) af[kt] = *(const int4v*)(hb + aoff[kt]);

    int4v acc0 = {0,0,0,0}, acc1 = {0,0,0,0}, acc2 = {0,0,0,0};
    #pragma unroll
    for (int kt=0; kt<4; kt++){
      acc0 = __builtin_amdgcn_mfma_i32_16x16x64_i8(af[kt], wq0[kt], acc0, 0,0,0);
      acc1 = __builtin_amdgcn_mfma_i32_16x16x64_i8(af[kt], wq1[kt], acc1, 0,0,0);
      acc2 = __builtin_amdgcn_mfma_i32_16x16x64_i8(af[kt], wq2[kt], acc2, 0,0,0);
    }

    const int te = (MODE==0 && !fwd) ? (127 - t) : t;
    signed char* nbuf = hbf + ((cur^1)<<12);
    #pragma unroll
    for (int r=0;r<4;r++){
      const int m = 4*lhi + r;
      const int tok = xsh[(m<<7) + te];
      const float* Gp = G + (size_t)tok*768;
      float gr = Gp[c], gz = Gp[256 + c], gn = Gp[512 + c];
      if (MODE==1){
        const float* zp = &zcs[m*768];
        gr += zp[c]; gz += zp[256 + c]; gn += zp[512 + c];
      }
      float ghr = (float)acc0[r] * isr;
      float ghz = (float)acc1[r] * isz;
      float ghn = (float)acc2[r] * isn;
      float rg = fast_sigmoid(ghr + gr);
      float zg = fast_sigmoid(ghz + gz);
      float nn = fast_tanh(gn + rg*(ghn + bnv));
      float hv = nn + zg*(hreg[r] - nn);
      hreg[r] = hv;
      int hq = __float2int_rn(fminf(fmaxf(hv*HS, -127.f), 127.f));
      nbuf[m*256 + (c ^ ((m&15)<<4))] = (signed char)hq;
      if (MODE == 1){
        ys[((size_t)(b0+m)*127 + t)*256 + c] = f2b(hv);
      }
    }
    __syncthreads();
    cur ^= 1;
  }

  if (MODE == 0){
    #pragma unroll
    for (int r=0;r<4;r++){
      const int m = 4*lhi + r;
      out_h[(size_t)(b0+m)*512 + (fwd ? 0 : 256) + c] = hreg[r];
    }
  }
}

// ---------------- VQ: z, argmin codebook, Q, idx, decoder h0, zc ----------------
__global__ __launch_bounds__(64) void k_vq(
    const float* __restrict__ outH, const float* __restrict__ Wdown, const float* __restrict__ bdown,
    const float* __restrict__ cb, const float* __restrict__ Wup, const float* __restrict__ bup,
    const float* __restrict__ Wihd, const float* __restrict__ bihd, const float* __restrict__ bhhd,
    float* __restrict__ hidden, float* __restrict__ zc, float* __restrict__ dout){
  const int b = blockIdx.x;
  const int lane = threadIdx.x;
  __shared__ float oh[512];
  __shared__ float zsh[32];
  __shared__ float qsh[32];
  {
    const float* src = outH + (size_t)b*512 + lane*8;
    *(float4*)&oh[lane*8]   = *(const float4*)src;
    *(float4*)&oh[lane*8+4] = *(const float4*)(src+4);
  }
  __syncthreads();
  if (lane < 32){
    float acc = bdown[lane];
    const float* wr = Wdown + lane*512;
    for (int k=0;k<512;k++) acc += wr[k]*oh[k];
    zsh[lane] = acc;
  }
  __syncthreads();
  float bd = 3.4e38f; int bi = 0;
  for (int c8=0;c8<8;c8++){
    const int c = lane*8 + c8;
    const float* cr = cb + c*32;
    float d = 0.f;
    #pragma unroll
    for (int k=0;k<32;k++){ float df = zsh[k]-cr[k]; d += df*df; }
    if (d < bd){ bd = d; bi = c; }
  }
  #pragma unroll
  for (int offm=32; offm>0; offm>>=1){
    float od = __shfl_xor(bd, offm);
    int   oi = __shfl_xor(bi, offm);
    if (od < bd || (od == bd && oi < bi)){ bd = od; bi = oi; }
  }
  if (lane == 0){
    atomicAdd(&dout[Q_OFF], bd * (0.2f/32.f));
    dout[IDX_OFF + b] = (float)bi;
  }
  if (lane < 32) qsh[lane] = cb[(size_t)bi*32 + lane];
  __syncthreads();
  #pragma unroll
  for (int i=0;i<4;i++){
    const int o = lane*4 + i;
    float acc = bup[o];
    const float* wr = Wup + o*32;
    #pragma unroll
    for (int k=0;k<32;k++) acc += wr[k]*qsh[k];
    hidden[(size_t)b*256 + o] = acc;
  }
  #pragma unroll
  for (int i=0;i<12;i++){
    const int o = lane*12 + i;
    float acc = bihd[o] + (o < 512 ? bhhd[o] : 0.f);
    const float* wr = Wihd + (size_t)o*96;
    #pragma unroll
    for (int k=0;k<32;k++) acc += wr[k]*qsh[k];
    zc[(size_t)b*768 + o] = acc;
  }
}

// ---------------- output: logits, log-softmax, nll, argmax ----------------
__global__ __launch_bounds__(256) void k_out(
    const u16* __restrict__ ys, const u16* __restrict__ Wo,
    const float* __restrict__ bout, const int* __restrict__ x,
    float* __restrict__ dout){
  const int tid = threadIdx.x;
  const int w = tid >> 6, lane = tid & 63;
  const int l15 = lane & 15, lhi = lane >> 4;
  __shared__ float lg[4][32][66];
  const int rows0 = blockIdx.x*128 + w*32;
  const f32x4 fz = {0.f,0.f,0.f,0.f};
  #pragma unroll
  for (int mt=0; mt<2; mt++){
    const int rb = rows0 + mt*16;
    f32x4 acc[4];
    #pragma unroll
    for (int nt=0;nt<4;nt++) acc[nt] = fz;
    #pragma unroll
    for (int kt=0; kt<8; kt++){
      short8 a = *(const short8*)&ys[(size_t)(rb + l15)*256 + kt*32 + lhi*8];
      #pragma unroll
      for (int nt=0; nt<4; nt++){
        short8 bb = *(const short8*)&Wo[(size_t)(nt*16 + l15)*256 + kt*32 + lhi*8];
        acc[nt] = __builtin_amdgcn_mfma_f32_16x16x32_bf16(a, bb, acc[nt], 0, 0, 0);
      }
    }
    #pragma unroll
    for (int nt=0;nt<4;nt++){
      const int col = nt*16 + l15;
      const float bo = (col < 51) ? bout[col] : 0.f;
      #pragma unroll
      for (int r=0;r<4;r++){
        float v = (col < 51) ? (acc[nt][r] + bo) : -1e30f;
        lg[w][mt*16 + lhi*4 + r][col] = v;
      }
    }
  }
  __syncthreads();
  float xl = 0.f, ct = 0.f;
  if (lane < 32){
    const int grow = rows0 + lane;
    const float* Lr = &lg[w][lane][0];
    float m = Lr[0]; int am = 0;
    for (int i=1;i<51;i++){ float v = Lr[i]; if (v > m){ m = v; am = i; } }
    float s = 0.f;
    for (int i=0;i<51;i++) s += __expf(Lr[i] - m);
    const int bb = grow / 127;
    const int tt = grow - bb*127;
    const int tgt = x[bb*128 + tt + 1];
    const float nll = (m + __logf(s)) - Lr[tgt];
    const float mk = (tgt != 0) ? 1.f : 0.f;
    dout[PRED_OFF + grow] = (float)am;
    xl = nll * mk; ct = mk;
  }
  #pragma unroll
  for (int off=32; off>0; off>>=1){
    xl += __shfl_xor(xl, off);
    ct += __shfl_xor(ct, off);
  }
  if (lane == 0){
    atomicAdd(&dout[XLOSS_OFF], xl);
    atomicAdd(&dout[NPAD_OFF], ct);
  }
}

extern "C" void kernel_launch(void* const* d_in, const int* in_sizes, int n_in,
                              void* d_out, int out_size, void* d_ws, size_t ws_size,
                              hipStream_t stream){
  (void)in_sizes; (void)n_in; (void)out_size; (void)ws_size;
  const int*   x      = (const int*)  d_in[0];
  const float* emb_e  = (const float*)d_in[1];
  const float* emb_d  = (const float*)d_in[2];
  const float* Wih_f  = (const float*)d_in[3];
  const float* Whh_f  = (const float*)d_in[4];
  const float* bih_f  = (const float*)d_in[5];
  const float* bhh_f  = (const float*)d_in[6];
  const float* Wih_b  = (const float*)d_in[7];
  const float* Whh_b  = (const float*)d_in[8];
  const float* bih_b  = (const float*)d_in[9];
  const float* bhh_b  = (const float*)d_in[10];
  const float* Wdown  = (const float*)d_in[11];
  const float* bdown  = (const float*)d_in[12];
  const float* cbook  = (const float*)d_in[13];
  const float* Wup    = (const float*)d_in[14];
  const float* bup    = (const float*)d_in[15];
  const float* Wih_d  = (const float*)d_in[16];
  const float* Whh_d  = (const float*)d_in[17];
  const float* bih_d  = (const float*)d_in[18];
  const float* bhh_d  = (const float*)d_in[19];
  const float* Wout   = (const float*)d_in[20];
  const float* bout   = (const float*)d_in[21];
  float* dout = (float*)d_out;

  char* ws = (char*)d_ws;
  size_t off = 0;
  auto nxt = [&](size_t bytes)->char*{
    char* r = ws + off;
    off += (bytes + 255) & ~(size_t)255;
    return r;
  };
  signed char* Wq_f = (signed char*)nxt((size_t)196608);
  signed char* Wq_b = (signed char*)nxt((size_t)196608);
  signed char* Wq_d = (signed char*)nxt((size_t)196608);
  float* invF = (float*)nxt((size_t)768*4);
  float* invB = (float*)nxt((size_t)768*4);
  float* invD = (float*)nxt((size_t)768*4);
  float* Gf    = (float*)nxt((size_t)39168*4);
  float* Gb    = (float*)nxt((size_t)39168*4);
  float* Gd    = (float*)nxt((size_t)39168*4);
  u16*   Wo_bf = (u16*)  nxt((size_t)16384*2);
  float* outH  = (float*)nxt((size_t)524288*4);
  float* hid   = (float*)nxt((size_t)262144*4);
  float* zcw   = (float*)nxt((size_t)786432*4);
  u16*   ysb   = (u16*)  nxt((size_t)33292288*2);

  hipLaunchKernelGGL(k_prep_wo, dim3(64), dim3(256), 0, stream, Wout, Wo_bf, dout);
  hipLaunchKernelGGL(k_prep_q, dim3(2304), dim3(64), 0, stream,
                     Whh_f, Whh_b, Whh_d, Wq_f, Wq_b, Wq_d, invF, invB, invD);
  hipLaunchKernelGGL(k_prep_g, dim3(459), dim3(256), 0, stream,
                     emb_e, emb_d, Wih_f, bih_f, bhh_f, Wih_b, bih_b, bhh_b, Wih_d,
                     Gf, Gb, Gd);
  hipLaunchKernelGGL((k_gru<0>), dim3(128), dim3(1024), 0, stream,
                     Wq_f, Wq_b, invF, invB, Gf, Gb, bhh_f, bhh_b, x,
                     (const float*)nullptr, (const float*)nullptr, outH, (u16*)nullptr);
  hipLaunchKernelGGL(k_vq, dim3(1024), dim3(64), 0, stream,
                     outH, Wdown, bdown, cbook, Wup, bup, Wih_d, bih_d, bhh_d,
                     hid, zcw, dout);
  hipLaunchKernelGGL((k_gru<1>), dim3(64), dim3(1024), 0, stream,
                     Wq_d, (const signed char*)nullptr, invD, (const float*)nullptr,
                     Gd, (const float*)nullptr, bhh_d, (const float*)nullptr, x,
                     zcw, hid, (float*)nullptr, ysb);
  hipLaunchKernelGGL(k_out, dim3(1016), dim3(256), 0, stream,
                     ysb, Wo_bf, bout, x, dout);
}